// Round 11
// baseline (108.085 us; speedup 1.0000x reference)
//
#include <hip/hip_runtime.h>

#define EPS 1e-6f

typedef unsigned short u16;
typedef u16   u16x4  __attribute__((ext_vector_type(4)));
typedef u16   u16x8  __attribute__((ext_vector_type(8)));
typedef float f32x4  __attribute__((ext_vector_type(4)));
typedef _Float16 f16x8 __attribute__((ext_vector_type(8)));

enum { BR_LIN = 0, BR_R6, BR_R5, BR_MIN, BR_R3, BR_XY, BR_R1, BR_R0 };

// ---------------- helpers ----------------
__device__ __forceinline__ u16 f2h(float f) { return __builtin_bit_cast(u16, (_Float16)f); }

__device__ __forceinline__ f16x8 lds_f16x8(const u16* p) {
  u16x8 r = *(const u16x8*)p;
  return __builtin_bit_cast(f16x8, r);
}

__device__ __forceinline__ f32x4 mfma16(f16x8 a, f16x8 b, f32x4 c) {
  return __builtin_amdgcn_mfma_f32_16x16x32_f16(a, b, c, 0, 0, 0);
}

__device__ __forceinline__ float r_poly_f(float a) {
  float d  = 0.5f - a;
  float d2 = d * d;
  float num = 0.25f + 1.65811f * d + 2.15388f * d2 + 8.2844f * d2 * d + 6.16764f * d2 * d2;
  float den = a * (1.0f - a);
  if (fabsf(den) < EPS) den = EPS;
  return num / den;
}

__device__ __forceinline__ float pmean(float X, float Y, float r, float rinv, float w0, float w1) {
  float tx = exp2f(r * log2f(X));
  float ty = exp2f(r * log2f(Y));
  float s  = w0 * tx + w1 * ty;
  return exp2f(rinv * log2f(s));
}

// branchy combine (legacy 8-float params) — fused fallback only
__device__ __forceinline__ float combine_step(float carry, float leaf, const float* p) {
  float w0 = p[0], w1 = p[1], a_fb = p[2];
  float c0 = p[3], c1 = p[4], c2 = p[5], c3 = p[6];
  int meta = __float_as_int(p[7]);
  int br = meta & 0xff, flip = meta >> 8;

  float xx = carry, yy = leaf;
  xx = __builtin_isnan(xx) ? EPS : xx;
  yy = __builtin_isnan(yy) ? EPS : yy;
  xx = fminf(fmaxf(xx, EPS), 1.0f - EPS);
  yy = fminf(fmaxf(yy, EPS), 1.0f - EPS);
  float X = flip ? (1.0f - xx) : xx;
  float Y = flip ? (1.0f - yy) : yy;

  float r;
  switch (br) {
    default:
    case BR_LIN: r = w0 * X + w1 * Y; break;
    case BR_R6:  r = c0 * (w0 * X + w1 * Y) + c1 * pmean(X, Y, c2, c3, w0, w1); break;
    case BR_R5:  r = pmean(X, Y, c0, c1, w0, w1); break;
    case BR_MIN: r = fminf(X, Y); break;
    case BR_R3:  r = 4.0f * (c0 * fminf(X, Y) + c1 * (X * Y)); break;
    case BR_XY:  r = X * Y; break;
    case BR_R1:  r = exp2f(c0 * log2f(X * Y)); break;
    case BR_R0:  r = (fabsf(X - 1.0f) < EPS && fabsf(Y - 1.0f) < EPS) ? 1.0f : 0.0f; break;
  }
  if (flip) r = 1.0f - r;
  if (__builtin_isnan(r)) r = a_fb;
  return r;
}

// branchless blended step (trimmed):
// p0=[fx,w0,w1,s_lin] p1=[s_mn,s_xy,s_pm,s_pow] p2=[rs,rinv,cp,sx]
__device__ __forceinline__ float step2(float carry, float leaf,
                                       f32x4 p0, f32x4 p1, f32x4 p2) {
  float fx = p0[0], w0 = p0[1], w1 = p0[2], s_lin = p0[3];
  float s_mn = p1[0], s_xy = p1[1], s_pm = p1[2], s_pow = p1[3];
  float rs = p2[0], rinv = p2[1], cp = p2[2], sx = p2[3];

  float xx = fminf(fmaxf(carry, EPS), 1.0f - EPS);
  float yy = fminf(fmaxf(leaf,  EPS), 1.0f - EPS);
  float X = fmaf(sx, xx, fx);
  float Y = fmaf(sx, yy, fx);

  float lx = log2f(X), ly = log2f(Y);
  float pw = exp2f(cp * (lx + ly));
  float ex = exp2f(rs * lx), ey = exp2f(rs * ly);
  float s  = fmaf(w0, ex, w1 * ey);
  float pm = exp2f(rinv * log2f(s));

  float r = s_lin * fmaf(w0, X, w1 * Y);
  r = fmaf(s_mn, fminf(X, Y), r);
  r = fmaf(s_xy, X * Y, r);
  r = fmaf(s_pm, pm, r);
  r = fmaf(s_pow, pw, r);
  return fmaf(sx, r, fx);
}

// ---------------- kernel 1: per-node params (legacy 8f + blended 12f) ----------------
__global__ void param_kernel(const float* __restrict__ W, const float* __restrict__ Bv,
                             float* __restrict__ prm8, float* __restrict__ prm12, int n) {
  int i = blockIdx.x * blockDim.x + threadIdx.x;
  if (i >= n) return;
  float w0r = W[2 * i], w1r = W[2 * i + 1];
  float m  = fmaxf(w0r, w1r);
  float e0 = expf(w0r - m), e1 = expf(w1r - m);
  float inv = 1.0f / (e0 + e1);
  float w0 = e0 * inv, w1 = e1 * inv;

  float b   = Bv[i];
  float sig = 1.0f / (1.0f + expf(-b));
  float a_fb = sig * 3.0f - 1.0f;

  float a = a_fb;
  if (__builtin_isnan(a)) a = -1.0f;
  a = fminf(fmaxf(a, -1.0f + EPS), 2.0f - EPS);
  int flip = (a < 0.5f - EPS) ? 1 : 0;
  float aa = a;
  if (flip) aa = fminf(fmaxf(1.0f - a, -1.0f + EPS), 2.0f - EPS);

  int br; float c0 = 0.f, c1 = 0.f, c2 = 0.f, c3 = 0.f;
  if (fabsf(aa - 2.0f) < EPS) br = BR_R0;
  else if (aa > 1.25f && aa < 2.0f) {
    br = BR_R1;
    c0 = sqrtf(fmaxf(3.0f / fmaxf(2.0f - aa, EPS) - 1.0f, EPS));
  } else if (fabsf(aa - 1.25f) < EPS) br = BR_XY;
  else if (aa > 1.0f && aa < 1.25f) { br = BR_R3; c0 = 1.25f - aa; c1 = aa - 1.0f; }
  else if (fabsf(aa - 1.0f) < EPS) br = BR_MIN;
  else if (aa >= 0.75f && aa < 1.0f) {
    br = BR_R5;
    float ac = fminf(fmaxf(aa, 0.75f), 1.0f - EPS);
    float ra = r_poly_f(ac);
    if (fabsf(ra) < EPS) ra = EPS;
    c0 = ra; c1 = 1.0f / ra;
  } else if (aa > 0.5f && aa < 0.75f) {
    br = BR_R6;
    c0 = 3.0f - 4.0f * aa; c1 = 4.0f * aa - 2.0f;
    float R = r_poly_f(0.75f);
    if (fabsf(R) < EPS) R = EPS;
    c2 = R; c3 = 1.0f / R;
  } else br = BR_LIN;

  float* o = prm8 + i * 8;
  o[0] = w0; o[1] = w1; o[2] = a_fb; o[3] = c0; o[4] = c1; o[5] = c2; o[6] = c3;
  o[7] = __int_as_float(br | (flip << 8));

  float s_lin = 0.f, s_mn = 0.f, s_xy = 0.f, s_pm = 0.f, s_pow = 0.f;
  float rs = 1.0f, rinv = 1.0f, cp = 0.0f;
  if (br == BR_R1)       { s_pow = 1.0f; cp = c0; }
  else if (br == BR_XY)  { s_xy = 1.0f; }
  else if (br == BR_R3)  { s_mn = 4.0f * c0; s_xy = 4.0f * c1; }
  else if (br == BR_MIN) { s_mn = 1.0f; }
  else if (br == BR_R5)  { s_pm = 1.0f; rs = c0; rinv = c1; }
  else if (br == BR_R6)  { s_lin = c0; s_pm = c1; rs = c2; rinv = c3; }
  else if (br == BR_LIN) { s_lin = 1.0f; }
  // BR_R0: all weights zero

  float* o12 = prm12 + i * 12;
  o12[0] = (float)flip; o12[1] = w0;  o12[2] = w1;   o12[3] = s_lin;
  o12[4] = s_mn;        o12[5] = s_xy; o12[6] = s_pm; o12[7] = s_pow;
  o12[8] = rs;          o12[9] = rinv; o12[10] = cp;  o12[11] = 1.0f - 2.0f * (float)flip;
}

// ---------------- kernel 2: register-resident Sinkhorn (fp16 PT out) ----------------
__global__ __launch_bounds__(1024, 4) void sinkhorn_kernel(
    const float* __restrict__ logits, u16* __restrict__ PTf) {
  __shared__ float alpha[256], beta[256];
  __shared__ float psum[256][33];

  const int t  = threadIdx.x;
  const int R  = t >> 5;
  const int C  = t & 31;
  const int r0 = R << 3;

  float e[8][8];
  #pragma unroll
  for (int dr = 0; dr < 8; ++dr) {
    const float* row = logits + (r0 + dr) * 256 + C;
    #pragma unroll
    for (int m = 0; m < 8; ++m) e[dr][m] = __expf(row[m << 5]);
  }

  if (t < 256) beta[t] = 1.0f;
  __syncthreads();

  for (int it = 0; it < 10; ++it) {
    {
      float bv[8], acc[8];
      #pragma unroll
      for (int m = 0; m < 8; ++m) bv[m] = beta[C + (m << 5)];
      #pragma unroll
      for (int dr = 0; dr < 8; ++dr) {
        float s = 0.f;
        #pragma unroll
        for (int m = 0; m < 8; ++m) s += e[dr][m] * bv[m];
        acc[dr] = s;
      }
      #pragma unroll
      for (int dr = 0; dr < 8; ++dr) psum[r0 + dr][C] = acc[dr];
    }
    __syncthreads();
    if (t < 256) {
      float s = 0.f;
      #pragma unroll
      for (int j = 0; j < 32; ++j) s += psum[t][j];
      alpha[t] = 1.0f / s;
    }
    __syncthreads();
    {
      float av[8], acc[8];
      #pragma unroll
      for (int dr = 0; dr < 8; ++dr) av[dr] = alpha[r0 + dr];
      #pragma unroll
      for (int m = 0; m < 8; ++m) {
        float s = 0.f;
        #pragma unroll
        for (int dr = 0; dr < 8; ++dr) s += e[dr][m] * av[dr];
        acc[m] = s;
      }
      #pragma unroll
      for (int m = 0; m < 8; ++m) psum[C + (m << 5)][R] = acc[m];
    }
    __syncthreads();
    if (t < 256) {
      float s = 0.f;
      #pragma unroll
      for (int j = 0; j < 32; ++j) s += psum[t][j];
      beta[t] = 1.0f / s;
    }
    __syncthreads();
  }

  float av[8], bv[8];
  #pragma unroll
  for (int dr = 0; dr < 8; ++dr) av[dr] = alpha[r0 + dr];
  #pragma unroll
  for (int m = 0; m < 8; ++m) bv[m] = beta[C + (m << 5)];

  #pragma unroll
  for (int m = 0; m < 8; ++m) {
    int l = C + (m << 5);
    u16x8 vh;
    #pragma unroll
    for (int dr = 0; dr < 8; ++dr) vh[dr] = f2h(av[dr] * e[dr][m] * bv[m]);
    *(u16x8*)(PTf + l * 256 + r0) = vh;
  }
}

// ---------------- kernel 3a: GEMM -> C[b][l] (transposed via LDS) ----------------
#define CSTR 132

__global__ __launch_bounds__(512, 4) void gemm_store_kernel(
    const float* __restrict__ x, const u16* __restrict__ PTf,
    float* __restrict__ C, int B) {
  __shared__ __align__(16) char smem[33792];
  u16* xs = (u16*)smem;                      // [128][32] fp16 (swizzled groups)
  u16* pt = (u16*)(smem + 8192);             // [256][32] fp16 (swizzled groups)
  float* cbuf = (float*)smem;                // [64][CSTR] epilogue alias

  const int t    = threadIdx.x;
  const int w    = t >> 6;
  const int lane = t & 63;
  const int bl   = lane & 15;
  const int kh   = lane >> 4;
  const int wm   = w >> 2;
  const int wn   = w & 3;
  const int b0   = blockIdx.x * 128;

  const int xrow = t >> 3;
  const int xc4  = t & 7;

  f32x4 acc[8][2];
  #pragma unroll
  for (int m = 0; m < 8; ++m) {
    acc[m][0] = f32x4{0.f, 0.f, 0.f, 0.f};
    acc[m][1] = f32x4{0.f, 0.f, 0.f, 0.f};
  }

  f32x4 xr[2];
  u16x8 pr[2];

  #pragma unroll
  for (int j = 0; j < 2; ++j) {
    xr[j] = *(const f32x4*)(x + (b0 + xrow + 64 * j) * 256 + (xc4 << 2));
    int c = t + 512 * j, r = c >> 2, s = c & 3, g = s ^ ((r >> 1) & 3);
    pr[j] = *(const u16x8*)(PTf + r * 256 + (g << 3));
  }

  for (int kc = 0; kc < 8; ++kc) {
    #pragma unroll
    for (int j = 0; j < 2; ++j) {
      int row = xrow + 64 * j;
      u16x4 hv;
      #pragma unroll
      for (int e = 0; e < 4; ++e) hv[e] = f2h(xr[j][e]);
      int g = xc4 >> 1, sub = xc4 & 1;
      *(u16x4*)(xs + row * 32 + ((g ^ ((row >> 1) & 3)) << 3) + (sub << 2)) = hv;
      *(u16x8*)(pt + ((t + 512 * j) << 3)) = pr[j];
    }
    __syncthreads();

    if (kc < 7) {
      int k1 = (kc + 1) << 5;
      #pragma unroll
      for (int j = 0; j < 2; ++j) {
        xr[j] = *(const f32x4*)(x + (b0 + xrow + 64 * j) * 256 + k1 + (xc4 << 2));
        int c = t + 512 * j, r = c >> 2, s = c & 3, g = s ^ ((r >> 1) & 3);
        pr[j] = *(const u16x8*)(PTf + r * 256 + k1 + (g << 3));
      }
    }

    f16x8 bh[2];
    #pragma unroll
    for (int nf = 0; nf < 2; ++nf) {
      int brow = (wn << 5) + (nf << 4) + bl;
      bh[nf] = lds_f16x8(xs + brow * 32 + ((kh ^ ((brow >> 1) & 3)) << 3));
    }
    #pragma unroll
    for (int mf = 0; mf < 8; ++mf) {
      int arow = (wm << 7) + (mf << 4) + bl;
      f16x8 ah = lds_f16x8(pt + arow * 32 + ((kh ^ ((arow >> 1) & 3)) << 3));
      #pragma unroll
      for (int nf = 0; nf < 2; ++nf)
        acc[mf][nf] = mfma16(ah, bh[nf], acc[mf][nf]);
    }
    __syncthreads();
  }

  // epilogue: per 64-l chunk, acc -> cbuf[l'][b] -> C[b][l] (16-l line per thread)
  const int sb = t & 127;                      // b within tile (wave-consecutive)
  const int sq = t >> 7;                       // 16-l slice within chunk

  #pragma unroll
  for (int c = 0; c < 4; ++c) {
    __syncthreads();
    if (wm == (c >> 1)) {
      #pragma unroll
      for (int d = 0; d < 4; ++d) {
        int mf = ((c & 1) << 2) + d;
        #pragma unroll
        for (int nf = 0; nf < 2; ++nf) {
          int bc = (wn << 5) + (nf << 4) + bl;
          #pragma unroll
          for (int r = 0; r < 4; ++r) {
            int lr = (d << 4) + (kh << 2) + r;
            cbuf[lr * CSTR + bc] = acc[mf][nf][r];
          }
        }
      }
    }
    __syncthreads();
    {
      f32x4 o0, o1, o2, o3;
      #pragma unroll
      for (int j = 0; j < 4; ++j) {
        o0[j] = cbuf[((sq << 4) + j)      * CSTR + sb];
        o1[j] = cbuf[((sq << 4) + j + 4)  * CSTR + sb];
        o2[j] = cbuf[((sq << 4) + j + 8)  * CSTR + sb];
        o3[j] = cbuf[((sq << 4) + j + 12) * CSTR + sb];
      }
      float* dst = C + (size_t)(b0 + sb) * 256 + (c << 6) + (sq << 4);
      *(f32x4*)(dst)      = o0;
      *(f32x4*)(dst + 4)  = o1;
      *(f32x4*)(dst + 8)  = o2;
      *(f32x4*)(dst + 12) = o3;
    }
  }
}

// ---------------- kernel 3b: chain over C[b][l], period-2 pipelined ----------------
__global__ __launch_bounds__(256) void chain_kernel(
    const float* __restrict__ C, const float* __restrict__ prm12,
    float* __restrict__ out, int B) {
  __shared__ __align__(16) float q[264 * 12];          // nodes 0..254 + zero pad
  for (int j = threadIdx.x; j < 264 * 12; j += 256)
    q[j] = (j < 255 * 12) ? prm12[j] : 0.0f;
  __syncthreads();

  const int b = blockIdx.x * 256 + threadIdx.x;
  const float* Cb = C + (size_t)b * 256;

  f32x4 head = *(const f32x4*)(Cb);
  float carry = head[0];

  // head steps: leaves 1..3 (nodes 0..2)
  #pragma unroll
  for (int u = 1; u <= 3; ++u) {
    const float* qp = q + (u - 1) * 12;
    carry = step2(carry, head[u],
                  *(const f32x4*)qp, *(const f32x4*)(qp + 4), *(const f32x4*)(qp + 8));
  }

  // groups g=1..63: leaves 4g..4g+3, nodes 4g-1..4g+2
  f32x4 pA[12], pB[12], vA, vB;
  {
    const float* qa = q + (4 * 1 - 1) * 12;
    #pragma unroll
    for (int u = 0; u < 12; ++u) pA[u] = *(const f32x4*)(qa + 4 * u);
    const float* qb = q + (4 * 2 - 1) * 12;
    #pragma unroll
    for (int u = 0; u < 12; ++u) pB[u] = *(const f32x4*)(qb + 4 * u);
    vA = *(const f32x4*)(Cb + 4);
    vB = *(const f32x4*)(Cb + 8);
  }

  for (int g = 1; g <= 61; g += 2) {
    #pragma unroll
    for (int u = 0; u < 4; ++u)
      carry = step2(carry, vA[u], pA[3 * u], pA[3 * u + 1], pA[3 * u + 2]);
    {
      const float* qa = q + (4 * (g + 2) - 1) * 12;
      #pragma unroll
      for (int u = 0; u < 12; ++u) pA[u] = *(const f32x4*)(qa + 4 * u);
      vA = *(const f32x4*)(Cb + 4 * (g + 2));
    }
    #pragma unroll
    for (int u = 0; u < 4; ++u)
      carry = step2(carry, vB[u], pB[3 * u], pB[3 * u + 1], pB[3 * u + 2]);
    {
      const float* qb = q + (4 * (g + 3) - 1) * 12;
      #pragma unroll
      for (int u = 0; u < 12; ++u) pB[u] = *(const f32x4*)(qb + 4 * u);
      vB = *(const f32x4*)(Cb + 4 * (g + 3));
    }
  }
  // final group 63 (in pA/vA)
  #pragma unroll
  for (int u = 0; u < 4; ++u)
    carry = step2(carry, vA[u], pA[3 * u], pA[3 * u + 1], pA[3 * u + 2]);

  out[b] = carry;
}

// ---------------- kernel 3 (fallback): fused GEMM + chain (round-6) ----------------
__global__ __launch_bounds__(512, 4) void gemm_chain_kernel(
    const float* __restrict__ x, const u16* __restrict__ PTf,
    const float* __restrict__ prm, float* __restrict__ out) {
  __shared__ __align__(16) char smem[41984];
  u16* xs = (u16*)smem;
  u16* pt = (u16*)(smem + 8192);
  float* cbuf = (float*)smem;
  float* cprm = (float*)(smem + 33792);

  const int t    = threadIdx.x;
  const int w    = t >> 6;
  const int lane = t & 63;
  const int bl   = lane & 15;
  const int kh   = lane >> 4;
  const int wm   = w >> 2;
  const int wn   = w & 3;
  const int b0   = blockIdx.x * 128;

  const int xrow = t >> 3;
  const int xc4  = t & 7;

  f32x4 acc[8][2];
  #pragma unroll
  for (int m = 0; m < 8; ++m) {
    acc[m][0] = f32x4{0.f, 0.f, 0.f, 0.f};
    acc[m][1] = f32x4{0.f, 0.f, 0.f, 0.f};
  }

  f32x4 xr[2];
  u16x8 pr[2];

  #pragma unroll
  for (int j = 0; j < 2; ++j) {
    xr[j] = *(const f32x4*)(x + (b0 + xrow + 64 * j) * 256 + (xc4 << 2));
    int c = t + 512 * j, r = c >> 2, s = c & 3, g = s ^ ((r >> 1) & 3);
    pr[j] = *(const u16x8*)(PTf + r * 256 + (g << 3));
  }

  for (int kc = 0; kc < 8; ++kc) {
    #pragma unroll
    for (int j = 0; j < 2; ++j) {
      int row = xrow + 64 * j;
      u16x4 hv;
      #pragma unroll
      for (int e = 0; e < 4; ++e) hv[e] = f2h(xr[j][e]);
      int g = xc4 >> 1, sub = xc4 & 1;
      *(u16x4*)(xs + row * 32 + ((g ^ ((row >> 1) & 3)) << 3) + (sub << 2)) = hv;
      *(u16x8*)(pt + ((t + 512 * j) << 3)) = pr[j];
    }
    __syncthreads();

    if (kc < 7) {
      int k1 = (kc + 1) << 5;
      #pragma unroll
      for (int j = 0; j < 2; ++j) {
        xr[j] = *(const f32x4*)(x + (b0 + xrow + 64 * j) * 256 + k1 + (xc4 << 2));
        int c = t + 512 * j, r = c >> 2, s = c & 3, g = s ^ ((r >> 1) & 3);
        pr[j] = *(const u16x8*)(PTf + r * 256 + k1 + (g << 3));
      }
    }

    f16x8 bh[2];
    #pragma unroll
    for (int nf = 0; nf < 2; ++nf) {
      int brow = (wn << 5) + (nf << 4) + bl;
      bh[nf] = lds_f16x8(xs + brow * 32 + ((kh ^ ((brow >> 1) & 3)) << 3));
    }
    #pragma unroll
    for (int mf = 0; mf < 8; ++mf) {
      int arow = (wm << 7) + (mf << 4) + bl;
      f16x8 ah = lds_f16x8(pt + arow * 32 + ((kh ^ ((arow >> 1) & 3)) << 3));
      #pragma unroll
      for (int nf = 0; nf < 2; ++nf)
        acc[mf][nf] = mfma16(ah, bh[nf], acc[mf][nf]);
    }
    __syncthreads();
  }

  for (int j = t; j < 2040; j += 512) cprm[j] = prm[j];

  float carry = 0.0f;

  #pragma unroll
  for (int c = 0; c < 4; ++c) {
    __syncthreads();
    if (wm == (c >> 1)) {
      #pragma unroll
      for (int d = 0; d < 4; ++d) {
        int mf = ((c & 1) << 2) + d;
        #pragma unroll
        for (int nf = 0; nf < 2; ++nf) {
          int bc = (wn << 5) + (nf << 4) + bl;
          #pragma unroll
          for (int r = 0; r < 4; ++r) {
            int lr = (d << 4) + (kh << 2) + r;
            cbuf[lr * CSTR + bc] = acc[mf][nf][r];
          }
        }
      }
    }
    __syncthreads();
    if (t < 128) {
      for (int lc = 0; lc < 64; lc += 4) {
        float v[4];
        #pragma unroll
        for (int u = 0; u < 4; ++u) v[u] = cbuf[(lc + u) * CSTR + t];
        #pragma unroll
        for (int u = 0; u < 4; ++u) {
          int l = (c << 6) + lc + u;
          carry = (l == 0) ? v[u] : combine_step(carry, v[u], cprm + ((l - 1) << 3));
        }
      }
    }
  }
  if (t < 128) out[b0 + t] = carry;
}

// ---------------- launch ----------------
extern "C" void kernel_launch(void* const* d_in, const int* in_sizes, int n_in,
                              void* d_out, int out_size, void* d_ws, size_t ws_size,
                              hipStream_t stream) {
  const float* x       = (const float*)d_in[0];   // (65536, 256)
  const float* logits  = (const float*)d_in[1];   // (256, 256)
  const float* weights = (const float*)d_in[2];   // (255, 2)
  const float* biases  = (const float*)d_in[3];   // (255,)
  float* out = (float*)d_out;                     // (65536, 1)

  char* ws = (char*)d_ws;
  int Btot = in_sizes[0] / 256;                   // 65536

  size_t Cbytes = (size_t)256 * (size_t)Btot * 4; // 64 MB
  size_t need   = Cbytes + 131072 + 12288 + 8192;

  if (ws_size >= need && (Btot % 256) == 0) {
    float* C     = (float*)ws;
    u16*   PTf   = (u16*)(ws + Cbytes);
    float* prm12 = (float*)(ws + Cbytes + 131072);
    float* prm8  = (float*)(ws + Cbytes + 131072 + 12288);

    param_kernel<<<1, 256, 0, stream>>>(weights, biases, prm8, prm12, 255);
    sinkhorn_kernel<<<1, 1024, 0, stream>>>(logits, PTf);
    gemm_store_kernel<<<Btot / 128, 512, 0, stream>>>(x, PTf, C, Btot);
    chain_kernel<<<Btot / 256, 256, 0, stream>>>(C, prm12, out, Btot);
  } else {
    u16*   PTf   = (u16*)ws;
    float* prm8  = (float*)(ws + 131072);
    float* prm12 = (float*)(ws + 131072 + 8192);

    param_kernel<<<1, 256, 0, stream>>>(weights, biases, prm8, prm12, 255);
    sinkhorn_kernel<<<1, 1024, 0, stream>>>(logits, PTf);
    gemm_chain_kernel<<<Btot / 128, 512, 0, stream>>>(x, PTf, prm8, out);
  }
}

// Round 12
// 85.555 us; speedup vs baseline: 1.2633x; 1.2633x over previous
//
#include <hip/hip_runtime.h>

#define EPS 1e-6f

typedef unsigned short u16;
typedef u16   u16x4  __attribute__((ext_vector_type(4)));
typedef u16   u16x8  __attribute__((ext_vector_type(8)));
typedef float f32x4  __attribute__((ext_vector_type(4)));
typedef _Float16 f16x8 __attribute__((ext_vector_type(8)));

enum { BR_LIN = 0, BR_R6, BR_R5, BR_MIN, BR_R3, BR_XY, BR_R1, BR_R0 };

// ---------------- helpers ----------------
__device__ __forceinline__ u16 f2h(float f) { return __builtin_bit_cast(u16, (_Float16)f); }

__device__ __forceinline__ f16x8 lds_f16x8(const u16* p) {
  u16x8 r = *(const u16x8*)p;
  return __builtin_bit_cast(f16x8, r);
}

__device__ __forceinline__ f32x4 mfma16(f16x8 a, f16x8 b, f32x4 c) {
  return __builtin_amdgcn_mfma_f32_16x16x32_f16(a, b, c, 0, 0, 0);
}

// hardware transcendentals: v_exp_f32 = 2^x, v_log_f32 = log2(x); 1 instr each.
// Safe here: log2 args in [1e-6, 1), exp2 args finite (underflow->0 is correct).
__device__ __forceinline__ float fexp2(float x) {
  float r; asm("v_exp_f32 %0, %1" : "=v"(r) : "v"(x)); return r;
}
__device__ __forceinline__ float flog2(float x) {
  float r; asm("v_log_f32 %0, %1" : "=v"(r) : "v"(x)); return r;
}

__device__ __forceinline__ float r_poly_f(float a) {
  float d  = 0.5f - a;
  float d2 = d * d;
  float num = 0.25f + 1.65811f * d + 2.15388f * d2 + 8.2844f * d2 * d + 6.16764f * d2 * d2;
  float den = a * (1.0f - a);
  if (fabsf(den) < EPS) den = EPS;
  return num / den;
}

__device__ __forceinline__ float pmean(float X, float Y, float r, float rinv, float w0, float w1) {
  float tx = exp2f(r * log2f(X));
  float ty = exp2f(r * log2f(Y));
  float s  = w0 * tx + w1 * ty;
  return exp2f(rinv * log2f(s));
}

// branchy combine (legacy 8-float params) — fused fallback only
__device__ __forceinline__ float combine_step(float carry, float leaf, const float* p) {
  float w0 = p[0], w1 = p[1], a_fb = p[2];
  float c0 = p[3], c1 = p[4], c2 = p[5], c3 = p[6];
  int meta = __float_as_int(p[7]);
  int br = meta & 0xff, flip = meta >> 8;

  float xx = carry, yy = leaf;
  xx = __builtin_isnan(xx) ? EPS : xx;
  yy = __builtin_isnan(yy) ? EPS : yy;
  xx = fminf(fmaxf(xx, EPS), 1.0f - EPS);
  yy = fminf(fmaxf(yy, EPS), 1.0f - EPS);
  float X = flip ? (1.0f - xx) : xx;
  float Y = flip ? (1.0f - yy) : yy;

  float r;
  switch (br) {
    default:
    case BR_LIN: r = w0 * X + w1 * Y; break;
    case BR_R6:  r = c0 * (w0 * X + w1 * Y) + c1 * pmean(X, Y, c2, c3, w0, w1); break;
    case BR_R5:  r = pmean(X, Y, c0, c1, w0, w1); break;
    case BR_MIN: r = fminf(X, Y); break;
    case BR_R3:  r = 4.0f * (c0 * fminf(X, Y) + c1 * (X * Y)); break;
    case BR_XY:  r = X * Y; break;
    case BR_R1:  r = exp2f(c0 * log2f(X * Y)); break;
    case BR_R0:  r = (fabsf(X - 1.0f) < EPS && fabsf(Y - 1.0f) < EPS) ? 1.0f : 0.0f; break;
  }
  if (flip) r = 1.0f - r;
  if (__builtin_isnan(r)) r = a_fb;
  return r;
}

// branchless blended step with HW transcendentals:
// p0=[fx,w0,w1,s_lin] p1=[s_mn,s_xy,s_pm,s_pow] p2=[rs,rinv,cp,sx]
__device__ __forceinline__ float step2(float carry, float leaf,
                                       f32x4 p0, f32x4 p1, f32x4 p2) {
  float fx = p0[0], w0 = p0[1], w1 = p0[2], s_lin = p0[3];
  float s_mn = p1[0], s_xy = p1[1], s_pm = p1[2], s_pow = p1[3];
  float rs = p2[0], rinv = p2[1], cp = p2[2], sx = p2[3];

  float xx = fminf(fmaxf(carry, EPS), 1.0f - EPS);
  float yy = fminf(fmaxf(leaf,  EPS), 1.0f - EPS);
  float X = fmaf(sx, xx, fx);
  float Y = fmaf(sx, yy, fx);

  float lx = flog2(X), ly = flog2(Y);
  float pw = fexp2(cp * (lx + ly));
  float ex = fexp2(rs * lx), ey = fexp2(rs * ly);
  float s  = fmaf(w0, ex, w1 * ey);
  float pm = fexp2(rinv * flog2(s));

  float r = s_lin * fmaf(w0, X, w1 * Y);
  r = fmaf(s_mn, fminf(X, Y), r);
  r = fmaf(s_xy, X * Y, r);
  r = fmaf(s_pm, pm, r);
  r = fmaf(s_pow, pw, r);
  return fmaf(sx, r, fx);
}

// ---------------- kernel 1: per-node params (legacy 8f + blended 12f) ----------------
__global__ void param_kernel(const float* __restrict__ W, const float* __restrict__ Bv,
                             float* __restrict__ prm8, float* __restrict__ prm12, int n) {
  int i = blockIdx.x * blockDim.x + threadIdx.x;
  if (i >= n) return;
  float w0r = W[2 * i], w1r = W[2 * i + 1];
  float m  = fmaxf(w0r, w1r);
  float e0 = expf(w0r - m), e1 = expf(w1r - m);
  float inv = 1.0f / (e0 + e1);
  float w0 = e0 * inv, w1 = e1 * inv;

  float b   = Bv[i];
  float sig = 1.0f / (1.0f + expf(-b));
  float a_fb = sig * 3.0f - 1.0f;

  float a = a_fb;
  if (__builtin_isnan(a)) a = -1.0f;
  a = fminf(fmaxf(a, -1.0f + EPS), 2.0f - EPS);
  int flip = (a < 0.5f - EPS) ? 1 : 0;
  float aa = a;
  if (flip) aa = fminf(fmaxf(1.0f - a, -1.0f + EPS), 2.0f - EPS);

  int br; float c0 = 0.f, c1 = 0.f, c2 = 0.f, c3 = 0.f;
  if (fabsf(aa - 2.0f) < EPS) br = BR_R0;
  else if (aa > 1.25f && aa < 2.0f) {
    br = BR_R1;
    c0 = sqrtf(fmaxf(3.0f / fmaxf(2.0f - aa, EPS) - 1.0f, EPS));
  } else if (fabsf(aa - 1.25f) < EPS) br = BR_XY;
  else if (aa > 1.0f && aa < 1.25f) { br = BR_R3; c0 = 1.25f - aa; c1 = aa - 1.0f; }
  else if (fabsf(aa - 1.0f) < EPS) br = BR_MIN;
  else if (aa >= 0.75f && aa < 1.0f) {
    br = BR_R5;
    float ac = fminf(fmaxf(aa, 0.75f), 1.0f - EPS);
    float ra = r_poly_f(ac);
    if (fabsf(ra) < EPS) ra = EPS;
    c0 = ra; c1 = 1.0f / ra;
  } else if (aa > 0.5f && aa < 0.75f) {
    br = BR_R6;
    c0 = 3.0f - 4.0f * aa; c1 = 4.0f * aa - 2.0f;
    float R = r_poly_f(0.75f);
    if (fabsf(R) < EPS) R = EPS;
    c2 = R; c3 = 1.0f / R;
  } else br = BR_LIN;

  float* o = prm8 + i * 8;
  o[0] = w0; o[1] = w1; o[2] = a_fb; o[3] = c0; o[4] = c1; o[5] = c2; o[6] = c3;
  o[7] = __int_as_float(br | (flip << 8));

  float s_lin = 0.f, s_mn = 0.f, s_xy = 0.f, s_pm = 0.f, s_pow = 0.f;
  float rs = 1.0f, rinv = 1.0f, cp = 0.0f;
  if (br == BR_R1)       { s_pow = 1.0f; cp = c0; }
  else if (br == BR_XY)  { s_xy = 1.0f; }
  else if (br == BR_R3)  { s_mn = 4.0f * c0; s_xy = 4.0f * c1; }
  else if (br == BR_MIN) { s_mn = 1.0f; }
  else if (br == BR_R5)  { s_pm = 1.0f; rs = c0; rinv = c1; }
  else if (br == BR_R6)  { s_lin = c0; s_pm = c1; rs = c2; rinv = c3; }
  else if (br == BR_LIN) { s_lin = 1.0f; }
  // BR_R0: all weights zero

  float* o12 = prm12 + i * 12;
  o12[0] = (float)flip; o12[1] = w0;  o12[2] = w1;   o12[3] = s_lin;
  o12[4] = s_mn;        o12[5] = s_xy; o12[6] = s_pm; o12[7] = s_pow;
  o12[8] = rs;          o12[9] = rinv; o12[10] = cp;  o12[11] = 1.0f - 2.0f * (float)flip;
}

// ---------------- kernel 2: register-resident Sinkhorn (fp16 PT out) ----------------
__global__ __launch_bounds__(1024, 4) void sinkhorn_kernel(
    const float* __restrict__ logits, u16* __restrict__ PTf) {
  __shared__ float alpha[256], beta[256];
  __shared__ float psum[256][33];

  const int t  = threadIdx.x;
  const int R  = t >> 5;
  const int C  = t & 31;
  const int r0 = R << 3;

  float e[8][8];
  #pragma unroll
  for (int dr = 0; dr < 8; ++dr) {
    const float* row = logits + (r0 + dr) * 256 + C;
    #pragma unroll
    for (int m = 0; m < 8; ++m) e[dr][m] = __expf(row[m << 5]);
  }

  if (t < 256) beta[t] = 1.0f;
  __syncthreads();

  for (int it = 0; it < 10; ++it) {
    {
      float bv[8], acc[8];
      #pragma unroll
      for (int m = 0; m < 8; ++m) bv[m] = beta[C + (m << 5)];
      #pragma unroll
      for (int dr = 0; dr < 8; ++dr) {
        float s = 0.f;
        #pragma unroll
        for (int m = 0; m < 8; ++m) s += e[dr][m] * bv[m];
        acc[dr] = s;
      }
      #pragma unroll
      for (int dr = 0; dr < 8; ++dr) psum[r0 + dr][C] = acc[dr];
    }
    __syncthreads();
    if (t < 256) {
      float s = 0.f;
      #pragma unroll
      for (int j = 0; j < 32; ++j) s += psum[t][j];
      alpha[t] = 1.0f / s;
    }
    __syncthreads();
    {
      float av[8], acc[8];
      #pragma unroll
      for (int dr = 0; dr < 8; ++dr) av[dr] = alpha[r0 + dr];
      #pragma unroll
      for (int m = 0; m < 8; ++m) {
        float s = 0.f;
        #pragma unroll
        for (int dr = 0; dr < 8; ++dr) s += e[dr][m] * av[dr];
        acc[m] = s;
      }
      #pragma unroll
      for (int m = 0; m < 8; ++m) psum[C + (m << 5)][R] = acc[m];
    }
    __syncthreads();
    if (t < 256) {
      float s = 0.f;
      #pragma unroll
      for (int j = 0; j < 32; ++j) s += psum[t][j];
      beta[t] = 1.0f / s;
    }
    __syncthreads();
  }

  float av[8], bv[8];
  #pragma unroll
  for (int dr = 0; dr < 8; ++dr) av[dr] = alpha[r0 + dr];
  #pragma unroll
  for (int m = 0; m < 8; ++m) bv[m] = beta[C + (m << 5)];

  #pragma unroll
  for (int m = 0; m < 8; ++m) {
    int l = C + (m << 5);
    u16x8 vh;
    #pragma unroll
    for (int dr = 0; dr < 8; ++dr) vh[dr] = f2h(av[dr] * e[dr][m] * bv[m]);
    *(u16x8*)(PTf + l * 256 + r0) = vh;
  }
}

// ---------------- kernel 3a: GEMM -> global C[l][b] (direct scatter, round-8) ----------------
__global__ __launch_bounds__(512, 4) void gemm_store_kernel(
    const float* __restrict__ x, const u16* __restrict__ PTf,
    float* __restrict__ C, int B) {
  __shared__ __align__(16) char smem[24576];
  u16* xs = (u16*)smem;
  u16* pt = (u16*)(smem + 8192);

  const int t    = threadIdx.x;
  const int w    = t >> 6;
  const int lane = t & 63;
  const int bl   = lane & 15;
  const int kh   = lane >> 4;
  const int wm   = w >> 2;
  const int wn   = w & 3;
  const int b0   = blockIdx.x * 128;

  const int xrow = t >> 3;
  const int xc4  = t & 7;

  f32x4 acc[8][2];
  #pragma unroll
  for (int m = 0; m < 8; ++m) {
    acc[m][0] = f32x4{0.f, 0.f, 0.f, 0.f};
    acc[m][1] = f32x4{0.f, 0.f, 0.f, 0.f};
  }

  f32x4 xr[2];
  u16x8 pr[2];

  #pragma unroll
  for (int j = 0; j < 2; ++j) {
    xr[j] = *(const f32x4*)(x + (b0 + xrow + 64 * j) * 256 + (xc4 << 2));
    int c = t + 512 * j, r = c >> 2, s = c & 3, g = s ^ ((r >> 1) & 3);
    pr[j] = *(const u16x8*)(PTf + r * 256 + (g << 3));
  }

  for (int kc = 0; kc < 8; ++kc) {
    #pragma unroll
    for (int j = 0; j < 2; ++j) {
      int row = xrow + 64 * j;
      u16x4 hv;
      #pragma unroll
      for (int e = 0; e < 4; ++e) hv[e] = f2h(xr[j][e]);
      int g = xc4 >> 1, sub = xc4 & 1;
      *(u16x4*)(xs + row * 32 + ((g ^ ((row >> 1) & 3)) << 3) + (sub << 2)) = hv;
      *(u16x8*)(pt + ((t + 512 * j) << 3)) = pr[j];
    }
    __syncthreads();

    if (kc < 7) {
      int k1 = (kc + 1) << 5;
      #pragma unroll
      for (int j = 0; j < 2; ++j) {
        xr[j] = *(const f32x4*)(x + (b0 + xrow + 64 * j) * 256 + k1 + (xc4 << 2));
        int c = t + 512 * j, r = c >> 2, s = c & 3, g = s ^ ((r >> 1) & 3);
        pr[j] = *(const u16x8*)(PTf + r * 256 + k1 + (g << 3));
      }
    }

    f16x8 bh[2];
    #pragma unroll
    for (int nf = 0; nf < 2; ++nf) {
      int brow = (wn << 5) + (nf << 4) + bl;
      bh[nf] = lds_f16x8(xs + brow * 32 + ((kh ^ ((brow >> 1) & 3)) << 3));
    }
    #pragma unroll
    for (int mf = 0; mf < 8; ++mf) {
      int arow = (wm << 7) + (mf << 4) + bl;
      f16x8 ah = lds_f16x8(pt + arow * 32 + ((kh ^ ((arow >> 1) & 3)) << 3));
      #pragma unroll
      for (int nf = 0; nf < 2; ++nf)
        acc[mf][nf] = mfma16(ah, bh[nf], acc[mf][nf]);
    }
    __syncthreads();
  }

  #pragma unroll
  for (int mf = 0; mf < 8; ++mf) {
    #pragma unroll
    for (int nf = 0; nf < 2; ++nf) {
      int bb = b0 + (wn << 5) + (nf << 4) + bl;
      #pragma unroll
      for (int r = 0; r < 4; ++r) {
        int l = (wm << 7) + (mf << 4) + (kh << 2) + r;
        C[(size_t)l * B + bb] = acc[mf][nf][r];
      }
    }
  }
}

// ---------------- kernel 3b: chain over C[l][b], period-2, HW trans ----------------
__global__ __launch_bounds__(256) void chain_kernel(
    const float* __restrict__ C, const float* __restrict__ prm12,
    float* __restrict__ out, int B) {
  __shared__ __align__(16) float q[255 * 12];
  for (int j = threadIdx.x; j < 255 * 12; j += 256) q[j] = prm12[j];
  __syncthreads();

  const int b = blockIdx.x * 256 + threadIdx.x;
  const size_t sB = (size_t)B;
  const float* Cb = C + b;

  float carry = Cb[0];

  // head: leaves 1..3 (nodes 0..2)
  {
    float h1 = Cb[sB], h2 = Cb[2 * sB], h3 = Cb[3 * sB];
    const float* q0 = q;
    carry = step2(carry, h1, *(const f32x4*)(q0),      *(const f32x4*)(q0 + 4),  *(const f32x4*)(q0 + 8));
    carry = step2(carry, h2, *(const f32x4*)(q0 + 12), *(const f32x4*)(q0 + 16), *(const f32x4*)(q0 + 20));
    carry = step2(carry, h3, *(const f32x4*)(q0 + 24), *(const f32x4*)(q0 + 28), *(const f32x4*)(q0 + 32));
  }

  // groups g=1..63: leaves 4g..4g+3, nodes 4g-1..4g+2
  f32x4 pA[12], pB[12];
  float vA[4], vB[4];
  {
    const float* qa = q + (4 * 1 - 1) * 12;
    #pragma unroll
    for (int u = 0; u < 12; ++u) pA[u] = *(const f32x4*)(qa + 4 * u);
    const float* qb = q + (4 * 2 - 1) * 12;
    #pragma unroll
    for (int u = 0; u < 12; ++u) pB[u] = *(const f32x4*)(qb + 4 * u);
    #pragma unroll
    for (int u = 0; u < 4; ++u) vA[u] = Cb[(4 + u) * sB];
    #pragma unroll
    for (int u = 0; u < 4; ++u) vB[u] = Cb[(8 + u) * sB];
  }

  for (int g = 1; g <= 61; g += 2) {
    #pragma unroll
    for (int u = 0; u < 4; ++u)
      carry = step2(carry, vA[u], pA[3 * u], pA[3 * u + 1], pA[3 * u + 2]);
    {
      const float* qa = q + (4 * (g + 2) - 1) * 12;
      #pragma unroll
      for (int u = 0; u < 12; ++u) pA[u] = *(const f32x4*)(qa + 4 * u);
      const float* ca = Cb + (size_t)(4 * (g + 2)) * sB;
      #pragma unroll
      for (int u = 0; u < 4; ++u) vA[u] = ca[u * sB];
    }
    #pragma unroll
    for (int u = 0; u < 4; ++u)
      carry = step2(carry, vB[u], pB[3 * u], pB[3 * u + 1], pB[3 * u + 2]);
    {
      const float* qb = q + (4 * (g + 3) - 1) * 12;
      #pragma unroll
      for (int u = 0; u < 12; ++u) pB[u] = *(const f32x4*)(qb + 4 * u);
      const float* cbp = Cb + (size_t)(4 * (g + 3)) * sB;
      #pragma unroll
      for (int u = 0; u < 4; ++u) vB[u] = cbp[u * sB];
    }
  }
  // final group 63 (in pA/vA)
  #pragma unroll
  for (int u = 0; u < 4; ++u)
    carry = step2(carry, vA[u], pA[3 * u], pA[3 * u + 1], pA[3 * u + 2]);

  out[b] = carry;
}

// ---------------- kernel 3 (fallback): fused GEMM + chain (round-6) ----------------
#define CSTR 132

__global__ __launch_bounds__(512, 4) void gemm_chain_kernel(
    const float* __restrict__ x, const u16* __restrict__ PTf,
    const float* __restrict__ prm, float* __restrict__ out) {
  __shared__ __align__(16) char smem[41984];
  u16* xs = (u16*)smem;
  u16* pt = (u16*)(smem + 8192);
  float* cbuf = (float*)smem;
  float* cprm = (float*)(smem + 33792);

  const int t    = threadIdx.x;
  const int w    = t >> 6;
  const int lane = t & 63;
  const int bl   = lane & 15;
  const int kh   = lane >> 4;
  const int wm   = w >> 2;
  const int wn   = w & 3;
  const int b0   = blockIdx.x * 128;

  const int xrow = t >> 3;
  const int xc4  = t & 7;

  f32x4 acc[8][2];
  #pragma unroll
  for (int m = 0; m < 8; ++m) {
    acc[m][0] = f32x4{0.f, 0.f, 0.f, 0.f};
    acc[m][1] = f32x4{0.f, 0.f, 0.f, 0.f};
  }

  f32x4 xr[2];
  u16x8 pr[2];

  #pragma unroll
  for (int j = 0; j < 2; ++j) {
    xr[j] = *(const f32x4*)(x + (b0 + xrow + 64 * j) * 256 + (xc4 << 2));
    int c = t + 512 * j, r = c >> 2, s = c & 3, g = s ^ ((r >> 1) & 3);
    pr[j] = *(const u16x8*)(PTf + r * 256 + (g << 3));
  }

  for (int kc = 0; kc < 8; ++kc) {
    #pragma unroll
    for (int j = 0; j < 2; ++j) {
      int row = xrow + 64 * j;
      u16x4 hv;
      #pragma unroll
      for (int e = 0; e < 4; ++e) hv[e] = f2h(xr[j][e]);
      int g = xc4 >> 1, sub = xc4 & 1;
      *(u16x4*)(xs + row * 32 + ((g ^ ((row >> 1) & 3)) << 3) + (sub << 2)) = hv;
      *(u16x8*)(pt + ((t + 512 * j) << 3)) = pr[j];
    }
    __syncthreads();

    if (kc < 7) {
      int k1 = (kc + 1) << 5;
      #pragma unroll
      for (int j = 0; j < 2; ++j) {
        xr[j] = *(const f32x4*)(x + (b0 + xrow + 64 * j) * 256 + k1 + (xc4 << 2));
        int c = t + 512 * j, r = c >> 2, s = c & 3, g = s ^ ((r >> 1) & 3);
        pr[j] = *(const u16x8*)(PTf + r * 256 + k1 + (g << 3));
      }
    }

    f16x8 bh[2];
    #pragma unroll
    for (int nf = 0; nf < 2; ++nf) {
      int brow = (wn << 5) + (nf << 4) + bl;
      bh[nf] = lds_f16x8(xs + brow * 32 + ((kh ^ ((brow >> 1) & 3)) << 3));
    }
    #pragma unroll
    for (int mf = 0; mf < 8; ++mf) {
      int arow = (wm << 7) + (mf << 4) + bl;
      f16x8 ah = lds_f16x8(pt + arow * 32 + ((kh ^ ((arow >> 1) & 3)) << 3));
      #pragma unroll
      for (int nf = 0; nf < 2; ++nf)
        acc[mf][nf] = mfma16(ah, bh[nf], acc[mf][nf]);
    }
    __syncthreads();
  }

  for (int j = t; j < 2040; j += 512) cprm[j] = prm[j];

  float carry = 0.0f;

  #pragma unroll
  for (int c = 0; c < 4; ++c) {
    __syncthreads();
    if (wm == (c >> 1)) {
      #pragma unroll
      for (int d = 0; d < 4; ++d) {
        int mf = ((c & 1) << 2) + d;
        #pragma unroll
        for (int nf = 0; nf < 2; ++nf) {
          int bc = (wn << 5) + (nf << 4) + bl;
          #pragma unroll
          for (int r = 0; r < 4; ++r) {
            int lr = (d << 4) + (kh << 2) + r;
            cbuf[lr * CSTR + bc] = acc[mf][nf][r];
          }
        }
      }
    }
    __syncthreads();
    if (t < 128) {
      for (int lc = 0; lc < 64; lc += 4) {
        float v[4];
        #pragma unroll
        for (int u = 0; u < 4; ++u) v[u] = cbuf[(lc + u) * CSTR + t];
        #pragma unroll
        for (int u = 0; u < 4; ++u) {
          int l = (c << 6) + lc + u;
          carry = (l == 0) ? v[u] : combine_step(carry, v[u], cprm + ((l - 1) << 3));
        }
      }
    }
  }
  if (t < 128) out[b0 + t] = carry;
}

// ---------------- launch ----------------
extern "C" void kernel_launch(void* const* d_in, const int* in_sizes, int n_in,
                              void* d_out, int out_size, void* d_ws, size_t ws_size,
                              hipStream_t stream) {
  const float* x       = (const float*)d_in[0];   // (65536, 256)
  const float* logits  = (const float*)d_in[1];   // (256, 256)
  const float* weights = (const float*)d_in[2];   // (255, 2)
  const float* biases  = (const float*)d_in[3];   // (255,)
  float* out = (float*)d_out;                     // (65536, 1)

  char* ws = (char*)d_ws;
  int Btot = in_sizes[0] / 256;                   // 65536

  size_t Cbytes = (size_t)256 * (size_t)Btot * 4; // 64 MB
  size_t need   = Cbytes + 131072 + 12288 + 8192;

  if (ws_size >= need && (Btot % 256) == 0) {
    float* C     = (float*)ws;
    u16*   PTf   = (u16*)(ws + Cbytes);
    float* prm12 = (float*)(ws + Cbytes + 131072);
    float* prm8  = (float*)(ws + Cbytes + 131072 + 12288);

    param_kernel<<<1, 256, 0, stream>>>(weights, biases, prm8, prm12, 255);
    sinkhorn_kernel<<<1, 1024, 0, stream>>>(logits, PTf);
    gemm_store_kernel<<<Btot / 128, 512, 0, stream>>>(x, PTf, C, Btot);
    chain_kernel<<<Btot / 256, 256, 0, stream>>>(C, prm12, out, Btot);
  } else {
    u16*   PTf   = (u16*)ws;
    float* prm8  = (float*)(ws + 131072);
    float* prm12 = (float*)(ws + 131072 + 8192);

    param_kernel<<<1, 256, 0, stream>>>(weights, biases, prm8, prm12, 255);
    sinkhorn_kernel<<<1, 1024, 0, stream>>>(logits, PTf);
    gemm_chain_kernel<<<Btot / 128, 512, 0, stream>>>(x, PTf, prm8, out);
  }
}

// Round 13
// 83.093 us; speedup vs baseline: 1.3008x; 1.0296x over previous
//
#include <hip/hip_runtime.h>

#define EPS 1e-6f

typedef unsigned short u16;
typedef u16   u16x4  __attribute__((ext_vector_type(4)));
typedef u16   u16x8  __attribute__((ext_vector_type(8)));
typedef float f32x4  __attribute__((ext_vector_type(4)));
typedef _Float16 f16x8 __attribute__((ext_vector_type(8)));

enum { BR_LIN = 0, BR_R6, BR_R5, BR_MIN, BR_R3, BR_XY, BR_R1, BR_R0 };

// ---------------- helpers ----------------
__device__ __forceinline__ u16 f2h(float f) { return __builtin_bit_cast(u16, (_Float16)f); }

__device__ __forceinline__ f16x8 lds_f16x8(const u16* p) {
  u16x8 r = *(const u16x8*)p;
  return __builtin_bit_cast(f16x8, r);
}

__device__ __forceinline__ f32x4 mfma16(f16x8 a, f16x8 b, f32x4 c) {
  return __builtin_amdgcn_mfma_f32_16x16x32_f16(a, b, c, 0, 0, 0);
}

// hardware transcendentals: v_exp_f32 = 2^x, v_log_f32 = log2(x); 1 instr each.
// Safe here: log2 args in [1e-6, 1), exp2 args finite (underflow->0 correct).
__device__ __forceinline__ float fexp2(float x) {
  float r; asm("v_exp_f32 %0, %1" : "=v"(r) : "v"(x)); return r;
}
__device__ __forceinline__ float flog2(float x) {
  float r; asm("v_log_f32 %0, %1" : "=v"(r) : "v"(x)); return r;
}

__device__ __forceinline__ float r_poly_f(float a) {
  float d  = 0.5f - a;
  float d2 = d * d;
  float num = 0.25f + 1.65811f * d + 2.15388f * d2 + 8.2844f * d2 * d + 6.16764f * d2 * d2;
  float den = a * (1.0f - a);
  if (fabsf(den) < EPS) den = EPS;
  return num / den;
}

// branchless blended step with HW transcendentals:
// p0=[fx,w0,w1,s_lin] p1=[s_mn,s_xy,s_pm,s_pow] p2=[rs,rinv,cp,sx]
__device__ __forceinline__ float step2(float carry, float leaf,
                                       f32x4 p0, f32x4 p1, f32x4 p2) {
  float fx = p0[0], w0 = p0[1], w1 = p0[2], s_lin = p0[3];
  float s_mn = p1[0], s_xy = p1[1], s_pm = p1[2], s_pow = p1[3];
  float rs = p2[0], rinv = p2[1], cp = p2[2], sx = p2[3];

  float xx = fminf(fmaxf(carry, EPS), 1.0f - EPS);
  float yy = fminf(fmaxf(leaf,  EPS), 1.0f - EPS);
  float X = fmaf(sx, xx, fx);
  float Y = fmaf(sx, yy, fx);

  float lx = flog2(X), ly = flog2(Y);
  float pw = fexp2(cp * (lx + ly));
  float ex = fexp2(rs * lx), ey = fexp2(rs * ly);
  float s  = fmaf(w0, ex, w1 * ey);
  float pm = fexp2(rinv * flog2(s));

  float r = s_lin * fmaf(w0, X, w1 * Y);
  r = fmaf(s_mn, fminf(X, Y), r);
  r = fmaf(s_xy, X * Y, r);
  r = fmaf(s_pm, pm, r);
  r = fmaf(s_pow, pw, r);
  return fmaf(sx, r, fx);
}

// ---------------- kernel 1: per-node blended params (12 floats) ----------------
__global__ void param_kernel(const float* __restrict__ W, const float* __restrict__ Bv,
                             float* __restrict__ prm12, int n) {
  int i = blockIdx.x * blockDim.x + threadIdx.x;
  if (i >= n) return;
  float w0r = W[2 * i], w1r = W[2 * i + 1];
  float m  = fmaxf(w0r, w1r);
  float e0 = expf(w0r - m), e1 = expf(w1r - m);
  float inv = 1.0f / (e0 + e1);
  float w0 = e0 * inv, w1 = e1 * inv;

  float b   = Bv[i];
  float sig = 1.0f / (1.0f + expf(-b));
  float a_fb = sig * 3.0f - 1.0f;

  float a = a_fb;
  if (__builtin_isnan(a)) a = -1.0f;
  a = fminf(fmaxf(a, -1.0f + EPS), 2.0f - EPS);
  int flip = (a < 0.5f - EPS) ? 1 : 0;
  float aa = a;
  if (flip) aa = fminf(fmaxf(1.0f - a, -1.0f + EPS), 2.0f - EPS);

  int br; float c0 = 0.f, c1 = 0.f, c2 = 0.f, c3 = 0.f;
  if (fabsf(aa - 2.0f) < EPS) br = BR_R0;
  else if (aa > 1.25f && aa < 2.0f) {
    br = BR_R1;
    c0 = sqrtf(fmaxf(3.0f / fmaxf(2.0f - aa, EPS) - 1.0f, EPS));
  } else if (fabsf(aa - 1.25f) < EPS) br = BR_XY;
  else if (aa > 1.0f && aa < 1.25f) { br = BR_R3; c0 = 1.25f - aa; c1 = aa - 1.0f; }
  else if (fabsf(aa - 1.0f) < EPS) br = BR_MIN;
  else if (aa >= 0.75f && aa < 1.0f) {
    br = BR_R5;
    float ac = fminf(fmaxf(aa, 0.75f), 1.0f - EPS);
    float ra = r_poly_f(ac);
    if (fabsf(ra) < EPS) ra = EPS;
    c0 = ra; c1 = 1.0f / ra;
  } else if (aa > 0.5f && aa < 0.75f) {
    br = BR_R6;
    c0 = 3.0f - 4.0f * aa; c1 = 4.0f * aa - 2.0f;
    float R = r_poly_f(0.75f);
    if (fabsf(R) < EPS) R = EPS;
    c2 = R; c3 = 1.0f / R;
  } else br = BR_LIN;

  float s_lin = 0.f, s_mn = 0.f, s_xy = 0.f, s_pm = 0.f, s_pow = 0.f;
  float rs = 1.0f, rinv = 1.0f, cp = 0.0f;
  if (br == BR_R1)       { s_pow = 1.0f; cp = c0; }
  else if (br == BR_XY)  { s_xy = 1.0f; }
  else if (br == BR_R3)  { s_mn = 4.0f * c0; s_xy = 4.0f * c1; }
  else if (br == BR_MIN) { s_mn = 1.0f; }
  else if (br == BR_R5)  { s_pm = 1.0f; rs = c0; rinv = c1; }
  else if (br == BR_R6)  { s_lin = c0; s_pm = c1; rs = c2; rinv = c3; }
  else if (br == BR_LIN) { s_lin = 1.0f; }
  // BR_R0: all weights zero (post-clamp X,Y < 1 -> reference r0 == 0 == empty sum)

  float* o12 = prm12 + i * 12;
  o12[0] = (float)flip; o12[1] = w0;  o12[2] = w1;   o12[3] = s_lin;
  o12[4] = s_mn;        o12[5] = s_xy; o12[6] = s_pm; o12[7] = s_pow;
  o12[8] = rs;          o12[9] = rinv; o12[10] = cp;  o12[11] = 1.0f - 2.0f * (float)flip;
}

// ---------------- kernel 2: register-resident Sinkhorn (fp16 PT out) ----------------
__global__ __launch_bounds__(1024, 4) void sinkhorn_kernel(
    const float* __restrict__ logits, u16* __restrict__ PTf) {
  __shared__ float alpha[256], beta[256];
  __shared__ float psum[256][33];

  const int t  = threadIdx.x;
  const int R  = t >> 5;
  const int C  = t & 31;
  const int r0 = R << 3;

  float e[8][8];
  #pragma unroll
  for (int dr = 0; dr < 8; ++dr) {
    const float* row = logits + (r0 + dr) * 256 + C;
    #pragma unroll
    for (int m = 0; m < 8; ++m) e[dr][m] = __expf(row[m << 5]);
  }

  if (t < 256) beta[t] = 1.0f;
  __syncthreads();

  for (int it = 0; it < 10; ++it) {
    {
      float bv[8], acc[8];
      #pragma unroll
      for (int m = 0; m < 8; ++m) bv[m] = beta[C + (m << 5)];
      #pragma unroll
      for (int dr = 0; dr < 8; ++dr) {
        float s = 0.f;
        #pragma unroll
        for (int m = 0; m < 8; ++m) s += e[dr][m] * bv[m];
        acc[dr] = s;
      }
      #pragma unroll
      for (int dr = 0; dr < 8; ++dr) psum[r0 + dr][C] = acc[dr];
    }
    __syncthreads();
    if (t < 256) {
      float s = 0.f;
      #pragma unroll
      for (int j = 0; j < 32; ++j) s += psum[t][j];
      alpha[t] = 1.0f / s;
    }
    __syncthreads();
    {
      float av[8], acc[8];
      #pragma unroll
      for (int dr = 0; dr < 8; ++dr) av[dr] = alpha[r0 + dr];
      #pragma unroll
      for (int m = 0; m < 8; ++m) {
        float s = 0.f;
        #pragma unroll
        for (int dr = 0; dr < 8; ++dr) s += e[dr][m] * av[dr];
        acc[m] = s;
      }
      #pragma unroll
      for (int m = 0; m < 8; ++m) psum[C + (m << 5)][R] = acc[m];
    }
    __syncthreads();
    if (t < 256) {
      float s = 0.f;
      #pragma unroll
      for (int j = 0; j < 32; ++j) s += psum[t][j];
      beta[t] = 1.0f / s;
    }
    __syncthreads();
  }

  float av[8], bv[8];
  #pragma unroll
  for (int dr = 0; dr < 8; ++dr) av[dr] = alpha[r0 + dr];
  #pragma unroll
  for (int m = 0; m < 8; ++m) bv[m] = beta[C + (m << 5)];

  #pragma unroll
  for (int m = 0; m < 8; ++m) {
    int l = C + (m << 5);
    u16x8 vh;
    #pragma unroll
    for (int dr = 0; dr < 8; ++dr) vh[dr] = f2h(av[dr] * e[dr][m] * bv[m]);
    *(u16x8*)(PTf + l * 256 + r0) = vh;
  }
}

// ---------------- kernel 3: fused fp16 GEMM + branchless HW-trans chain ----------------
// 512 thr = 8 waves (2M x 4N), b-tile 128, K-step 32, swizzled LDS (0 conflicts).
// Epilogue: acc -> cbuf (LDS) per 64-l chunk; waves 0-1 run the 256-step chain
// (step2, params in LDS). No global C round-trip.
// LDS map: staging xs@0 (8K) pt@8192 (16K) | epilogue cbuf@0 (33792) q@33792 (12240).
#define CSTR 132

__global__ __launch_bounds__(512, 4) void gemm_chain_kernel(
    const float* __restrict__ x, const u16* __restrict__ PTf,
    const float* __restrict__ prm12, float* __restrict__ out) {
  __shared__ __align__(16) char smem[46080];
  u16* xs = (u16*)smem;                      // [128][32] fp16 (swizzled groups)
  u16* pt = (u16*)(smem + 8192);             // [256][32] fp16 (swizzled groups)
  float* cbuf = (float*)smem;                // [64][CSTR] epilogue alias
  float* qlds = (float*)(smem + 33792);      // 3060 floats (node params)

  const int t    = threadIdx.x;
  const int w    = t >> 6;
  const int lane = t & 63;
  const int bl   = lane & 15;
  const int kh   = lane >> 4;
  const int wm   = w >> 2;                   // 0..1
  const int wn   = w & 3;                    // 0..3
  const int b0   = blockIdx.x * 128;

  const int xrow = t >> 3;
  const int xc4  = t & 7;

  // chain params into LDS (region disjoint from staging; visible after k-loop barriers)
  for (int j = t; j < 3060; j += 512) qlds[j] = prm12[j];

  f32x4 acc[8][2];
  #pragma unroll
  for (int m = 0; m < 8; ++m) {
    acc[m][0] = f32x4{0.f, 0.f, 0.f, 0.f};
    acc[m][1] = f32x4{0.f, 0.f, 0.f, 0.f};
  }

  f32x4 xr[2];
  u16x8 pr[2];

  #pragma unroll
  for (int j = 0; j < 2; ++j) {
    xr[j] = *(const f32x4*)(x + (b0 + xrow + 64 * j) * 256 + (xc4 << 2));
    int c = t + 512 * j, r = c >> 2, s = c & 3, g = s ^ ((r >> 1) & 3);
    pr[j] = *(const u16x8*)(PTf + r * 256 + (g << 3));
  }

  for (int kc = 0; kc < 8; ++kc) {
    #pragma unroll
    for (int j = 0; j < 2; ++j) {
      int row = xrow + 64 * j;
      u16x4 hv;
      #pragma unroll
      for (int e = 0; e < 4; ++e) hv[e] = f2h(xr[j][e]);
      int g = xc4 >> 1, sub = xc4 & 1;
      *(u16x4*)(xs + row * 32 + ((g ^ ((row >> 1) & 3)) << 3) + (sub << 2)) = hv;
      *(u16x8*)(pt + ((t + 512 * j) << 3)) = pr[j];
    }
    __syncthreads();

    if (kc < 7) {
      int k1 = (kc + 1) << 5;
      #pragma unroll
      for (int j = 0; j < 2; ++j) {
        xr[j] = *(const f32x4*)(x + (b0 + xrow + 64 * j) * 256 + k1 + (xc4 << 2));
        int c = t + 512 * j, r = c >> 2, s = c & 3, g = s ^ ((r >> 1) & 3);
        pr[j] = *(const u16x8*)(PTf + r * 256 + k1 + (g << 3));
      }
    }

    f16x8 bh[2];
    #pragma unroll
    for (int nf = 0; nf < 2; ++nf) {
      int brow = (wn << 5) + (nf << 4) + bl;
      bh[nf] = lds_f16x8(xs + brow * 32 + ((kh ^ ((brow >> 1) & 3)) << 3));
    }
    #pragma unroll
    for (int mf = 0; mf < 8; ++mf) {
      int arow = (wm << 7) + (mf << 4) + bl;
      f16x8 ah = lds_f16x8(pt + arow * 32 + ((kh ^ ((arow >> 1) & 3)) << 3));
      #pragma unroll
      for (int nf = 0; nf < 2; ++nf)
        acc[mf][nf] = mfma16(ah, bh[nf], acc[mf][nf]);
    }
    __syncthreads();
  }

  // ---- fused chain epilogue ----
  float carry = 0.0f;

  #pragma unroll
  for (int c = 0; c < 4; ++c) {
    __syncthreads();
    // waves with wm == c>>1 dump l-chunk [64c, 64c+64) into cbuf[l'][b]
    if (wm == (c >> 1)) {
      #pragma unroll
      for (int d = 0; d < 4; ++d) {
        int mf = ((c & 1) << 2) + d;
        #pragma unroll
        for (int nf = 0; nf < 2; ++nf) {
          int bc = (wn << 5) + (nf << 4) + bl;
          #pragma unroll
          for (int r = 0; r < 4; ++r) {
            int lr = (d << 4) + (kh << 2) + r;
            cbuf[lr * CSTR + bc] = acc[mf][nf][r];
          }
        }
      }
    }
    __syncthreads();
    if (t < 128) {
      int lc0 = 0;
      if (c == 0) {
        // leaves 0..3: init carry, then nodes 0..2
        float v0 = cbuf[0 * CSTR + t];
        float v1 = cbuf[1 * CSTR + t];
        float v2 = cbuf[2 * CSTR + t];
        float v3 = cbuf[3 * CSTR + t];
        carry = v0;
        carry = step2(carry, v1, *(const f32x4*)(qlds),      *(const f32x4*)(qlds + 4),  *(const f32x4*)(qlds + 8));
        carry = step2(carry, v2, *(const f32x4*)(qlds + 12), *(const f32x4*)(qlds + 16), *(const f32x4*)(qlds + 20));
        carry = step2(carry, v3, *(const f32x4*)(qlds + 24), *(const f32x4*)(qlds + 28), *(const f32x4*)(qlds + 32));
        lc0 = 4;
      }
      for (int lc = lc0; lc < 64; lc += 4) {
        float v[4];
        #pragma unroll
        for (int u = 0; u < 4; ++u) v[u] = cbuf[(lc + u) * CSTR + t];
        #pragma unroll
        for (int u = 0; u < 4; ++u) {
          int node = (c << 6) + lc + u - 1;
          const float* qn = qlds + node * 12;
          carry = step2(carry, v[u],
                        *(const f32x4*)(qn), *(const f32x4*)(qn + 4), *(const f32x4*)(qn + 8));
        }
      }
    }
  }
  if (t < 128) out[b0 + t] = carry;
}

// ---------------- launch ----------------
extern "C" void kernel_launch(void* const* d_in, const int* in_sizes, int n_in,
                              void* d_out, int out_size, void* d_ws, size_t ws_size,
                              hipStream_t stream) {
  const float* x       = (const float*)d_in[0];   // (65536, 256)
  const float* logits  = (const float*)d_in[1];   // (256, 256)
  const float* weights = (const float*)d_in[2];   // (255, 2)
  const float* biases  = (const float*)d_in[3];   // (255,)
  float* out = (float*)d_out;                     // (65536, 1)

  char* ws = (char*)d_ws;
  int Btot = in_sizes[0] / 256;                   // 65536

  u16*   PTf   = (u16*)ws;                        // 131072 B (fp16 P^T)
  float* prm12 = (float*)(ws + 131072);           // 12240 B

  param_kernel<<<1, 256, 0, stream>>>(weights, biases, prm12, 255);
  sinkhorn_kernel<<<1, 1024, 0, stream>>>(logits, PTf);
  gemm_chain_kernel<<<Btot / 128, 512, 0, stream>>>(x, PTf, prm12, out);
}